// Round 1
// baseline (580.052 us; speedup 1.0000x reference)
//
#include <hip/hip_runtime.h>
#include <hip/hip_bf16.h>

// Chamfer distance, B=16, N=M=4096, D=3, fp32 — ONE-PASS both-direction MFMA.
//
// Key change vs previous version: the 4096x4096 d2 matrix per batch is
// computed ONCE (rows=src via A-frags, cols=tgt via B-frags) and BOTH mins
// are extracted from it:
//   row-min (over cols)  -> cham_x : in-lane accumulate over col-tiles +
//                                    final cross-lane fold (masks 1..16)
//   col-min (over rows)  -> cham_y : in-lane 16-reg tree per MFMA result
//                                    (+ shfl32 to merge row-halves), stored
//                                    as per-strip partials, folded by K2.
// This halves MFMA / staging / load work outright.
//
// K0 pre-builds bf16 hi/lo split fragments once per point (prev version
// converted each target point 16x — once per strip-block).
// K1 waves split COLUMNS (wave w owns tiles t%4==w), so every col-tile is
// owned by one wave: B-frags stream global->VGPR (L2-resident, 1KB/tile
// coalesced), NO LDS staging, NO main-loop barriers. 2 blocks/CU.
// K2 folds the 32 strip partial col-mins (8MB) and atomicAdds.

#define BATCH   16
#define NPTS    4096
#define STRIPS  32                 // 128 rows per K1 block
#define ROWS_PB 128
#define NTILES  128                // 4096/32 col tiles
#define TPW     32                 // tiles per wave
#define NSTEP   16                 // ct-pair steps per wave

typedef __attribute__((ext_vector_type(8)))  short short8;
typedef __attribute__((ext_vector_type(16))) float float16;

union U4S8 { uint4 u; short8 s; };

__device__ inline unsigned int bfb(float v) {
    __hip_bfloat16 h = __float2bfloat16(v);
    unsigned short u; __builtin_memcpy(&u, &h, 2);
    return (unsigned int)u;
}
__device__ inline float bff(float v) { return __bfloat162float(__float2bfloat16(v)); }

#define ONEB 0x3F80u

// A (query) slots: [xh yh zh xh yh zh xl yl | zl fh fl 1 1 0 0 0]
__device__ inline void buildA(float x, float y, float z, uint4& w0, uint4& w1) {
    float xhf = bff(x), yhf = bff(y), zhf = bff(z);
    float f = fmaf(x, x, fmaf(y, y, z * z));
    float fhf = bff(f);
    unsigned xh = bfb(xhf), yh = bfb(yhf), zh = bfb(zhf);
    unsigned xl = bfb(x - xhf), yl = bfb(y - yhf), zl = bfb(z - zhf);
    unsigned fh = bfb(fhf), fl = bfb(f - fhf);
    w0 = make_uint4(xh | (yh << 16), zh | (xh << 16),
                    yh | (zh << 16), xl | (yl << 16));
    w1 = make_uint4(zl | (fh << 16), fl | (ONEB << 16), ONEB, 0u);
}

// B (target) slots: [-2xh -2yh -2zh -2xl -2yl -2zl -2xh -2yh | -2zh 1 1 fh fl 0 0 0]
__device__ inline void buildB(float x, float y, float z, uint4& w0, uint4& w1) {
    float xhf = bff(x), yhf = bff(y), zhf = bff(z);
    float f = fmaf(x, x, fmaf(y, y, z * z));
    float fhf = bff(f);
    unsigned a = bfb(-2.0f * xhf), b = bfb(-2.0f * yhf), c = bfb(-2.0f * zhf);
    unsigned d = bfb(-2.0f * (x - xhf)), e = bfb(-2.0f * (y - yhf)),
             g = bfb(-2.0f * (z - zhf));
    unsigned fh = bfb(fhf), fl = bfb(f - fhf);
    w0 = make_uint4(a | (b << 16), c | (d << 16),
                    e | (g << 16), a | (b << 16));
    w1 = make_uint4(c | (ONEB << 16), ONEB | (fh << 16), fl, 0u);
}

// ---------------------------------------------------------------- K0: frags
__global__ __launch_bounds__(256) void build_frags(
    const float* __restrict__ src, const float* __restrict__ tgt,
    uint4* __restrict__ wsA, uint4* __restrict__ wsB)
{
    int p = blockIdx.x * 256 + threadIdx.x;       // 0 .. 131071
    int tensor = p >> 16;                         // 0 = src->A, 1 = tgt->B
    int lp = p & 0xFFFF;                          // b*4096 + idx
    const float* raw = (tensor ? tgt : src) + (size_t)lp * 3;
    float x = raw[0], y = raw[1], z = raw[2];
    uint4 w0, w1;
    if (tensor) { buildB(x, y, z, w0, w1); wsB[2*lp] = w0; wsB[2*lp+1] = w1; }
    else        { buildA(x, y, z, w0, w1); wsA[2*lp] = w0; wsA[2*lp+1] = w1; }
}

// ---------------------------------------------------------------- K1: main
__device__ inline float min16(const float16& a) {   // 8 v_min3-class ops
    float m0 = fminf(fminf(a[0],  a[1]),  a[2]);
    float m1 = fminf(fminf(a[3],  a[4]),  a[5]);
    float m2 = fminf(fminf(a[6],  a[7]),  a[8]);
    float m3 = fminf(fminf(a[9],  a[10]), a[11]);
    float m4 = fminf(fminf(a[12], a[13]), a[14]);
    float p0 = fminf(fminf(m0, m1), a[15]);
    float p1 = fminf(fminf(m2, m3), m4);
    return fminf(p0, p1);
}

__global__ __launch_bounds__(256, 2) void chamfer_main(
    const uint4* __restrict__ wsA, const uint4* __restrict__ wsB,
    float* __restrict__ wsC, float* __restrict__ out)
{
    __shared__ float rowpart[4][ROWS_PB];   // 2 KB: per-wave row-min partials
    __shared__ float wsum[4];

    int blk = blockIdx.x;
    const int strip = blk & (STRIPS - 1);
    const int b     = blk >> 5;

    const int t    = threadIdx.x;
    const int lane = t & 63;
    const int w    = t >> 6;        // wave owns col tiles {k: k%4==w}
    const int h    = lane >> 5;     // K-half / row-half
    const int l5   = lane & 31;

    const uint4* Af = wsA + (size_t)b * NPTS * 2;
    const uint4* Bf = wsB + (size_t)b * NPTS * 2;
    const size_t cbase = (size_t)(b * STRIPS + strip) * NPTS;

    // A fragments: 4 row-groups of 32 (128 rows per block), from ws.
    short8 afr[4];
#pragma unroll
    for (int g = 0; g < 4; g++) {
        int row = strip * ROWS_PB + g * 32 + l5;
        U4S8 tt; tt.u = Af[2 * row + h];
        afr[g] = tt.s;
    }

    const float16 z16 = {0.f,0.f,0.f,0.f,0.f,0.f,0.f,0.f,
                         0.f,0.f,0.f,0.f,0.f,0.f,0.f,0.f};
    float rm[4][16];
#pragma unroll
    for (int g = 0; g < 4; g++)
#pragma unroll
        for (int r = 0; r < 16; r++) rm[g][r] = 1e30f;

    // B-frag index for tile k of this wave: 1KB per tile, set-dense per wave.
    // lane(h,l5) reads word h of point (tile*32+l5).
    U4S8 cA, cB, nA, nB;
    cA.u = Bf[(w    ) * 64 + 2 * l5 + h];
    cB.u = Bf[(w + 4) * 64 + 2 * l5 + h];

#pragma unroll 4
    for (int s = 0; s < NSTEP; s++) {
        // prefetch next ct pair (wrap re-read on last iter: harmless, L2-hit)
        const int nk = (2 * s + 2) & (TPW - 1);
        nA.u = Bf[(w + 4 * nk    ) * 64 + 2 * l5 + h];
        nB.u = Bf[(w + 4 * nk + 4) * 64 + 2 * l5 + h];

        float cmA = 1e30f, cmB = 1e30f;
#pragma unroll
        for (int g = 0; g < 4; g++) {
            float16 aA = __builtin_amdgcn_mfma_f32_32x32x16_bf16(afr[g], cA.s, z16, 0, 0, 0);
            float16 aB = __builtin_amdgcn_mfma_f32_32x32x16_bf16(afr[g], cB.s, z16, 0, 0, 0);
#pragma unroll
            for (int r = 0; r < 16; r++)                       // v_min3
                rm[g][r] = fminf(fminf(aA[r], aB[r]), rm[g][r]);
            cmA = fminf(cmA, min16(aA));                       // col partial
            cmB = fminf(cmB, min16(aB));
        }
        // merge the two row-halves for the same col, then store partials
        cmA = fminf(cmA, __shfl_xor(cmA, 32, 64));
        cmB = fminf(cmB, __shfl_xor(cmB, 32, 64));
        if (h == 0) {
            const int tA = w + 8 * s;
            wsC[cbase + tA * 32 + l5]       = cmA;
            wsC[cbase + (tA + 4) * 32 + l5] = cmB;
        }
        cA = nA; cB = nB;
    }

    // Row-min: fold the 32 cols held across lanes (masks 1..16; halves hold
    // disjoint row sets so mask 32 must NOT fold).
#pragma unroll
    for (int mask = 1; mask <= 16; mask <<= 1)
#pragma unroll
        for (int g = 0; g < 4; g++)
#pragma unroll
            for (int r = 0; r < 16; r++)
                rm[g][r] = fminf(rm[g][r], __shfl_xor(rm[g][r], mask, 64));

    // lanes 0 and 32 now hold this wave's 2x64 row partials; stash in LDS.
    if (l5 == 0) {
#pragma unroll
        for (int g = 0; g < 4; g++)
#pragma unroll
            for (int r = 0; r < 16; r++)
                rowpart[w][g * 32 + (r & 3) + 8 * (r >> 2) + 4 * h] = rm[g][r];
    }
    __syncthreads();

    // fold across the 4 waves (different col ranges, same rows), clamp, sum.
    float s = 0.0f;
    if (t < ROWS_PB) {
        float v = fminf(fminf(rowpart[0][t], rowpart[1][t]),
                        fminf(rowpart[2][t], rowpart[3][t]));
        s = fmaxf(v, 0.0f);
    }
#pragma unroll
    for (int mask = 1; mask <= 32; mask <<= 1) s += __shfl_xor(s, mask, 64);
    if (lane == 0) wsum[w] = s;
    __syncthreads();
    if (t == 0)
        atomicAdd(out, (wsum[0] + wsum[1] + wsum[2] + wsum[3]) * (1.0f / (float)NPTS));
}

// ---------------------------------------------------------------- K2: cols
__global__ __launch_bounds__(256) void col_reduce(
    const float* __restrict__ wsC, float* __restrict__ out)
{
    __shared__ float wsum[4];
    const int b     = blockIdx.x >> 4;
    const int chunk = blockIdx.x & 15;
    const int col   = chunk * 256 + threadIdx.x;
    const float* base = wsC + (size_t)b * STRIPS * NPTS + col;

    float m = base[0];
#pragma unroll
    for (int s = 1; s < STRIPS; s++) m = fminf(m, base[(size_t)s * NPTS]);
    float v = fmaxf(m, 0.0f);
#pragma unroll
    for (int mask = 1; mask <= 32; mask <<= 1) v += __shfl_xor(v, mask, 64);
    if ((threadIdx.x & 63) == 0) wsum[threadIdx.x >> 6] = v;
    __syncthreads();
    if (threadIdx.x == 0)
        atomicAdd(out, (wsum[0] + wsum[1] + wsum[2] + wsum[3]) * (1.0f / (float)NPTS));
}

// ---------------------------------------------------------------- launch
extern "C" void kernel_launch(void* const* d_in, const int* in_sizes, int n_in,
                              void* d_out, int out_size, void* d_ws, size_t ws_size,
                              hipStream_t stream)
{
    const float* src = (const float*)d_in[0];
    const float* tgt = (const float*)d_in[1];
    float* out = (float*)d_out;

    // ws layout: [A-frags 2MB][B-frags 2MB][col partials 8MB] = 12 MB
    uint4* wsA = (uint4*)d_ws;
    uint4* wsB = wsA + (size_t)BATCH * NPTS * 2;
    float* wsC = (float*)(wsB + (size_t)BATCH * NPTS * 2);

    hipMemsetAsync(out, 0, sizeof(float), stream);
    build_frags <<<512, 256, 0, stream>>>(src, tgt, wsA, wsB);
    chamfer_main<<<BATCH * STRIPS, 256, 0, stream>>>(wsA, wsB, wsC, out);
    col_reduce  <<<BATCH * 16, 256, 0, stream>>>(wsC, out);
}

// Round 2
// 349.019 us; speedup vs baseline: 1.6620x; 1.6620x over previous
//
#include <hip/hip_runtime.h>
#include <hip/hip_bf16.h>

// Chamfer distance, B=16, N=M=4096, D=3, fp32 — one-pass MFMA, both mins.
//
// Structure = the proven 78us kernel's skeleton (in-block bf16 hi/lo frag
// conversion -> LDS staging -> prefetched ds_read_b128 -> 4 back-to-back
// 32x32x16 MFMAs -> v_min3 folds), with the dir(2) duplication replaced by
// col-min extraction from the SAME d2 tiles (one-pass math proven exact,
// absmax==0, in round 1):
//   row-min -> cham_x : rm[2][16] accumulate + cross-lane fold (masks 1..16),
//                       partial per col-quarter -> wsR[4][b][row]
//   col-min -> cham_y : per-step elementwise fmin(g0,g1) + min3 tree +
//                       shfl_xor(32) -> wsC[(b,strip,wave)][col] partials
// Grid: q(4 col-quarters) x b(16) x strip(16) = 1024 blocks x 256 thr.
// Each block: 256 rows x 1024 cols, ONE 32KB LDS buffer, ONE barrier,
// 16 j2-steps. 4 blocks/CU (LDS 33KB). finish_reduce folds 64 col-planes +
// 4 row-planes, clamps, sums, one atomicAdd per block.

#define BATCH   16
#define NPTS    4096
#define NSTRIPS 16                 // 256 rows per block
#define NQ      4                  // col quarters, 1024 cols per block
#define CHUNKC  1024
#define NSTEP   (CHUNKC / 64)      // 16 j2-steps

typedef __attribute__((ext_vector_type(8)))  short short8;
typedef __attribute__((ext_vector_type(16))) float float16;

union U4S8 { uint4 u; short8 s; };

__device__ inline unsigned int bfb(float v) {
    __hip_bfloat16 h = __float2bfloat16(v);
    unsigned short u; __builtin_memcpy(&u, &h, 2);
    return (unsigned int)u;
}
__device__ inline float bff(float v) { return __bfloat162float(__float2bfloat16(v)); }

#define ONEB 0x3F80u

// A (query) slots: [xh yh zh xh yh zh xl yl | zl fh fl 1 1 0 0 0]
__device__ inline void buildA(float x, float y, float z, uint4& w0, uint4& w1) {
    float xhf = bff(x), yhf = bff(y), zhf = bff(z);
    float f = fmaf(x, x, fmaf(y, y, z * z));
    float fhf = bff(f);
    unsigned xh = bfb(xhf), yh = bfb(yhf), zh = bfb(zhf);
    unsigned xl = bfb(x - xhf), yl = bfb(y - yhf), zl = bfb(z - zhf);
    unsigned fh = bfb(fhf), fl = bfb(f - fhf);
    w0 = make_uint4(xh | (yh << 16), zh | (xh << 16),
                    yh | (zh << 16), xl | (yl << 16));
    w1 = make_uint4(zl | (fh << 16), fl | (ONEB << 16), ONEB, 0u);
}

// B (target) slots: [-2xh -2yh -2zh -2xl -2yl -2zl -2xh -2yh | -2zh 1 1 fh fl 0 0 0]
__device__ inline void buildB(float x, float y, float z, uint4& w0, uint4& w1) {
    float xhf = bff(x), yhf = bff(y), zhf = bff(z);
    float f = fmaf(x, x, fmaf(y, y, z * z));
    float fhf = bff(f);
    unsigned a = bfb(-2.0f * xhf), b = bfb(-2.0f * yhf), c = bfb(-2.0f * zhf);
    unsigned d = bfb(-2.0f * (x - xhf)), e = bfb(-2.0f * (y - yhf)),
             g = bfb(-2.0f * (z - zhf));
    unsigned fh = bfb(fhf), fl = bfb(f - fhf);
    w0 = make_uint4(a | (b << 16), c | (d << 16),
                    e | (g << 16), a | (b << 16));
    w1 = make_uint4(c | (ONEB << 16), ONEB | (fh << 16), fl, 0u);
}

// min over rows of one col-tile: elementwise pair fmin then min3 tree.
__device__ inline float min16pair(const float16& a, const float16& b) {
    float t0  = fminf(a[0],  b[0]),  t1  = fminf(a[1],  b[1]);
    float t2  = fminf(a[2],  b[2]),  t3  = fminf(a[3],  b[3]);
    float t4  = fminf(a[4],  b[4]),  t5  = fminf(a[5],  b[5]);
    float t6  = fminf(a[6],  b[6]),  t7  = fminf(a[7],  b[7]);
    float t8  = fminf(a[8],  b[8]),  t9  = fminf(a[9],  b[9]);
    float t10 = fminf(a[10], b[10]), t11 = fminf(a[11], b[11]);
    float t12 = fminf(a[12], b[12]), t13 = fminf(a[13], b[13]);
    float t14 = fminf(a[14], b[14]), t15 = fminf(a[15], b[15]);
    float m0 = fminf(fminf(t0,  t1),  t2);    // v_min3
    float m1 = fminf(fminf(t3,  t4),  t5);
    float m2 = fminf(fminf(t6,  t7),  t8);
    float m3 = fminf(fminf(t9,  t10), t11);
    float m4 = fminf(fminf(t12, t13), t14);
    float p0 = fminf(fminf(m0, m1), t15);
    float p1 = fminf(fminf(m2, m3), m4);
    return fminf(p0, p1);
}

__global__ __launch_bounds__(256, 3) void chamfer_main(
    const float* __restrict__ src, const float* __restrict__ tgt,
    float* __restrict__ wsC, float* __restrict__ wsR)
{
    __shared__ uint4 sbuf[2][CHUNKC];   // 32 KB: [half][pt]
    __shared__ float rowpart[256];      // 1 KB

    int blk = blockIdx.x;
    const int strip = blk & (NSTRIPS - 1); blk >>= 4;
    const int b     = blk & 15;            blk >>= 4;
    const int q     = blk;                 // col quarter 0..3

    const int t    = threadIdx.x;
    const int lane = t & 63;
    const int w    = t >> 6;
    const int h    = lane >> 5;
    const int l5   = lane & 31;

    const float* Araw = src + (size_t)b * NPTS * 3;   // rows (queries)
    const float* Braw = tgt + (size_t)b * NPTS * 3;   // cols (targets)

    // raw B loads for this block's 1024 cols (issue early, convert later)
    float nx[4][3];
#pragma unroll
    for (int k = 0; k < 4; k++) {
        int p = q * CHUNKC + t + k * 256;
        nx[k][0] = Braw[3 * p + 0];
        nx[k][1] = Braw[3 * p + 1];
        nx[k][2] = Braw[3 * p + 2];
    }

    // A fragments: 2 row-groups of 32 rows per wave (256 rows per block)
    short8 afr[2];
#pragma unroll
    for (int g = 0; g < 2; g++) {
        int row = strip * 256 + g * 128 + w * 32 + l5;
        uint4 w0, w1;
        buildA(Araw[3 * row], Araw[3 * row + 1], Araw[3 * row + 2], w0, w1);
        U4S8 tt; tt.u = h ? w1 : w0;
        afr[g] = tt.s;
    }

    // convert + stage B fragments
#pragma unroll
    for (int k = 0; k < 4; k++) {
        int lp = t + k * 256;
        uint4 w0, w1;
        buildB(nx[k][0], nx[k][1], nx[k][2], w0, w1);
        sbuf[0][lp] = w0;
        sbuf[1][lp] = w1;
    }
    __syncthreads();

    const float16 z16 = {0.f,0.f,0.f,0.f,0.f,0.f,0.f,0.f,
                         0.f,0.f,0.f,0.f,0.f,0.f,0.f,0.f};
    float rm[2][16];
#pragma unroll
    for (int g = 0; g < 2; g++)
#pragma unroll
        for (int r = 0; r < 16; r++) rm[g][r] = 1e30f;

    // col-partial plane for (b, strip, w), offset by this quarter's cols
    float* cdst = wsC + ((size_t)((b * NSTRIPS + strip) * 4 + w)) * NPTS
                      + q * CHUNKC;

    U4S8 c0, c1, n0, n1;
    c0.u = sbuf[h][l5];
    c1.u = sbuf[h][32 + l5];
#pragma unroll 4
    for (int j2 = 0; j2 < NSTEP; j2++) {
        int nj = (j2 + 1) & (NSTEP - 1);          // wrap re-read: harmless
        n0.u = sbuf[h][nj * 64 + l5];
        n1.u = sbuf[h][nj * 64 + 32 + l5];
        float16 a00 = __builtin_amdgcn_mfma_f32_32x32x16_bf16(afr[0], c0.s, z16, 0, 0, 0);
        float16 a01 = __builtin_amdgcn_mfma_f32_32x32x16_bf16(afr[0], c1.s, z16, 0, 0, 0);
        float16 a10 = __builtin_amdgcn_mfma_f32_32x32x16_bf16(afr[1], c0.s, z16, 0, 0, 0);
        float16 a11 = __builtin_amdgcn_mfma_f32_32x32x16_bf16(afr[1], c1.s, z16, 0, 0, 0);
#pragma unroll
        for (int r = 0; r < 16; r++) {
            rm[0][r] = fminf(fminf(a00[r], a01[r]), rm[0][r]);   // v_min3
            rm[1][r] = fminf(fminf(a10[r], a11[r]), rm[1][r]);
        }
        // col-mins of the two 32-col tiles (min over both row-groups)
        float cm0 = min16pair(a00, a10);
        float cm1 = min16pair(a01, a11);
        cm0 = fminf(cm0, __shfl_xor(cm0, 32, 64));   // merge row-halves
        cm1 = fminf(cm1, __shfl_xor(cm1, 32, 64));
        if (h == 0) {
            cdst[j2 * 64 + l5]      = cm0;
            cdst[j2 * 64 + 32 + l5] = cm1;
        }
        c0 = n0; c1 = n1;
    }

    // Row-min partial fold within wave (cols of this quarter only)
#pragma unroll
    for (int mask = 1; mask <= 16; mask <<= 1)
#pragma unroll
        for (int g = 0; g < 2; g++)
#pragma unroll
            for (int r = 0; r < 16; r++)
                rm[g][r] = fminf(rm[g][r], __shfl_xor(rm[g][r], mask, 64));

    // stash per-wave row partials (64 rows each) via LDS, write coalesced
    if (l5 == 0) {
#pragma unroll
        for (int g = 0; g < 2; g++)
#pragma unroll
            for (int r = 0; r < 16; r++)
                rowpart[w * 64 + g * 32 + (r & 3) + 8 * (r >> 2) + 4 * h] = rm[g][r];
    }
    __syncthreads();
    {
        const int w2 = t >> 6, g2 = (t >> 5) & 1, idx = t & 31;
        const int grow = strip * 256 + g2 * 128 + w2 * 32 + idx;
        wsR[((size_t)q * BATCH + b) * NPTS + grow] = rowpart[w2 * 64 + g2 * 32 + idx];
    }
}

// ------------------------------------------------- K2: fold partials + sum
__global__ __launch_bounds__(256) void finish_reduce(
    const float* __restrict__ wsC, const float* __restrict__ wsR,
    float* __restrict__ out)
{
    __shared__ float wsum[4];
    const int b     = blockIdx.x >> 4;
    const int chunk = blockIdx.x & 15;
    const int idx   = chunk * 256 + threadIdx.x;     // col index == row index

    // cham_y: fold 64 col-partial planes (16 strips x 4 waves)
    const float* cbase = wsC + (size_t)b * 64 * NPTS + idx;
    float m = cbase[0];
#pragma unroll 8
    for (int p = 1; p < 64; p++) m = fminf(m, cbase[(size_t)p * NPTS]);
    float v = fmaxf(m, 0.0f);

    // cham_x: fold 4 row-partial planes (col quarters)
    float r0 = wsR[((size_t)0 * BATCH + b) * NPTS + idx];
    float r1 = wsR[((size_t)1 * BATCH + b) * NPTS + idx];
    float r2 = wsR[((size_t)2 * BATCH + b) * NPTS + idx];
    float r3 = wsR[((size_t)3 * BATCH + b) * NPTS + idx];
    v += fmaxf(fminf(fminf(r0, r1), fminf(r2, r3)), 0.0f);

    const int lane = threadIdx.x & 63;
#pragma unroll
    for (int mask = 1; mask <= 32; mask <<= 1) v += __shfl_xor(v, mask, 64);
    if (lane == 0) wsum[threadIdx.x >> 6] = v;
    __syncthreads();
    if (threadIdx.x == 0)
        atomicAdd(out, (wsum[0] + wsum[1] + wsum[2] + wsum[3]) * (1.0f / (float)NPTS));
}

// ---------------------------------------------------------------- launch
extern "C" void kernel_launch(void* const* d_in, const int* in_sizes, int n_in,
                              void* d_out, int out_size, void* d_ws, size_t ws_size,
                              hipStream_t stream)
{
    const float* src = (const float*)d_in[0];
    const float* tgt = (const float*)d_in[1];
    float* out = (float*)d_out;

    // ws: [wsC 16MB: (b,strip,wave) x 4096 cols][wsR 1MB: (q,b) x 4096 rows]
    float* wsC = (float*)d_ws;
    float* wsR = wsC + (size_t)BATCH * NSTRIPS * 4 * NPTS;

    hipMemsetAsync(out, 0, sizeof(float), stream);
    chamfer_main <<<NQ * BATCH * NSTRIPS, 256, 0, stream>>>(src, tgt, wsC, wsR);
    finish_reduce<<<BATCH * 16, 256, 0, stream>>>(wsC, wsR, out);
}

// Round 3
// 82.503 us; speedup vs baseline: 7.0307x; 4.2304x over previous
//
#include <hip/hip_runtime.h>
#include <hip/hip_bf16.h>

// Chamfer distance, B=16, N=M=4096, D=3, fp32 — one-pass MFMA, both mins,
// MINIMAL workspace footprint (256 KB of uint atomicMin cells only).
//
// Lesson from rounds 1-2: any design streaming multi-MB buffers through
// d_ws showed ~50x HBM write amplification and a ~90%-stalled kernel
// (335-525us). This version keeps the PROVEN round-0 skeleton (in-block
// bf16 hi/lo frag conversion -> LDS dbuf staging -> prefetched ds_read ->
// back-to-back MFMAs -> v_min3 folds) and adds one-pass col-min extraction
// (math proven exact, absmax==0, twice):
//   row-min -> cham_x : rm[16] in-lane accum + cross-lane fold, final per
//                       block (block owns its 128 rows) -> atomicAdd(out)
//   col-min -> cham_y : per-step 8-op min3 tree per tile -> clamped uint
//                       atomicMin into block-local LDS plane; ONE global
//                       atomicMin per col per block at the end (256 KB ws,
//                       2M 4B atomics total). finish_reduce sums them.
// Grid: 512 blocks (32 strips x 16 b) x 256 thr; LDS 48KB -> 3 blocks/CU.
// Total MFMA / ds_read / staging work is HALF of the 78us two-pass kernel.

#define BATCH   16
#define NPTS    4096
#define NSTRIPS 32                 // 128 rows per block
#define CHUNKC  512
#define NCHUNKS (NPTS / CHUNKC)    // 8
#define NSTEP   (CHUNKC / 64)      // 8 j2-steps per chunk

typedef __attribute__((ext_vector_type(8)))  short short8;
typedef __attribute__((ext_vector_type(16))) float float16;

union U4S8 { uint4 u; short8 s; };

__device__ inline unsigned int bfb(float v) {
    __hip_bfloat16 h = __float2bfloat16(v);
    unsigned short u; __builtin_memcpy(&u, &h, 2);
    return (unsigned int)u;
}
__device__ inline float bff(float v) { return __bfloat162float(__float2bfloat16(v)); }

#define ONEB 0x3F80u

// A (query) slots: [xh yh zh xh yh zh xl yl | zl fh fl 1 1 0 0 0]
__device__ inline void buildA(float x, float y, float z, uint4& w0, uint4& w1) {
    float xhf = bff(x), yhf = bff(y), zhf = bff(z);
    float f = fmaf(x, x, fmaf(y, y, z * z));
    float fhf = bff(f);
    unsigned xh = bfb(xhf), yh = bfb(yhf), zh = bfb(zhf);
    unsigned xl = bfb(x - xhf), yl = bfb(y - yhf), zl = bfb(z - zhf);
    unsigned fh = bfb(fhf), fl = bfb(f - fhf);
    w0 = make_uint4(xh | (yh << 16), zh | (xh << 16),
                    yh | (zh << 16), xl | (yl << 16));
    w1 = make_uint4(zl | (fh << 16), fl | (ONEB << 16), ONEB, 0u);
}

// B (target) slots: [-2xh -2yh -2zh -2xl -2yl -2zl -2xh -2yh | -2zh 1 1 fh fl 0 0 0]
__device__ inline void buildB(float x, float y, float z, uint4& w0, uint4& w1) {
    float xhf = bff(x), yhf = bff(y), zhf = bff(z);
    float f = fmaf(x, x, fmaf(y, y, z * z));
    float fhf = bff(f);
    unsigned a = bfb(-2.0f * xhf), b = bfb(-2.0f * yhf), c = bfb(-2.0f * zhf);
    unsigned d = bfb(-2.0f * (x - xhf)), e = bfb(-2.0f * (y - yhf)),
             g = bfb(-2.0f * (z - zhf));
    unsigned fh = bfb(fhf), fl = bfb(f - fhf);
    w0 = make_uint4(a | (b << 16), c | (d << 16),
                    e | (g << 16), a | (b << 16));
    w1 = make_uint4(c | (ONEB << 16), ONEB | (fh << 16), fl, 0u);
}

// min over the 16 regs (this half's 16 rows) of one 32x32 MFMA result.
__device__ inline float tree16(const float16& a) {
    float m0 = fminf(fminf(a[0],  a[1]),  a[2]);    // v_min3
    float m1 = fminf(fminf(a[3],  a[4]),  a[5]);
    float m2 = fminf(fminf(a[6],  a[7]),  a[8]);
    float m3 = fminf(fminf(a[9],  a[10]), a[11]);
    float m4 = fminf(fminf(a[12], a[13]), a[14]);
    float p0 = fminf(fminf(m0, m1), a[15]);
    float p1 = fminf(fminf(m2, m3), m4);
    return fminf(p0, p1);
}

__global__ __launch_bounds__(256, 3) void chamfer_main(
    const float* __restrict__ src, const float* __restrict__ tgt,
    unsigned* __restrict__ wsC, float* __restrict__ out)
{
    __shared__ uint4 sbuf[2][2][CHUNKC];    // [buf][half][pt] = 32 KB
    __shared__ unsigned colpart[NPTS];      // 16 KB block-local col-mins
    __shared__ float wsum[4];

    int blk = blockIdx.x;
    const int strip = blk & (NSTRIPS - 1);
    const int b     = blk >> 5;

    const int t    = threadIdx.x;
    const int lane = t & 63;
    const int w    = t >> 6;
    const int h    = lane >> 5;
    const int l5   = lane & 31;

    const float* Araw = src + (size_t)b * NPTS * 3;   // rows (queries)
    const float* Braw = tgt + (size_t)b * NPTS * 3;   // cols (targets)

    // A fragment: one 32-row group per wave (128 rows per block)
    short8 afr;
    {
        int row = strip * 128 + w * 32 + l5;
        uint4 w0, w1;
        buildA(Araw[3 * row], Araw[3 * row + 1], Araw[3 * row + 2], w0, w1);
        U4S8 tt; tt.u = h ? w1 : w0;
        afr = tt.s;
    }

    // init block-local col-min plane
#pragma unroll
    for (int i = 0; i < 16; i++) colpart[t + i * 256] = 0xFFFFFFFFu;

    // Pipelined B staging: raw loads (regs) early, convert + ds_write late.
    float nx[2][3];
    auto loadRaw = [&](int c) {
#pragma unroll
        for (int k = 0; k < 2; k++) {
            int p = c * CHUNKC + t + k * 256;
            nx[k][0] = Braw[3 * p + 0];
            nx[k][1] = Braw[3 * p + 1];
            nx[k][2] = Braw[3 * p + 2];
        }
    };
    auto convertWrite = [&](int bi) {
#pragma unroll
        for (int k = 0; k < 2; k++) {
            int lp = t + k * 256;
            uint4 w0, w1;
            buildB(nx[k][0], nx[k][1], nx[k][2], w0, w1);
            sbuf[bi][0][lp] = w0;
            sbuf[bi][1][lp] = w1;
        }
    };

    const float16 z16 = {0.f,0.f,0.f,0.f,0.f,0.f,0.f,0.f,
                         0.f,0.f,0.f,0.f,0.f,0.f,0.f,0.f};
    float rm[16];
#pragma unroll
    for (int r = 0; r < 16; r++) rm[r] = 1e30f;

    loadRaw(0);
    convertWrite(0);
    for (int c = 0; c < NCHUNKS; c++) {
        __syncthreads();              // buf[c&1] written; prior-iter reads done
        if (c + 1 < NCHUNKS) loadRaw(c + 1);   // issue, don't wait
        const int bi = c & 1;

        U4S8 c0, c1, n0, n1;
        c0.u = sbuf[bi][h][l5];
        c1.u = sbuf[bi][h][32 + l5];
#pragma unroll 4
        for (int j2 = 0; j2 < NSTEP; j2++) {
            int nj = (j2 + 1) & (NSTEP - 1);          // wrap re-read: harmless
            n0.u = sbuf[bi][h][nj * 64 + l5];
            n1.u = sbuf[bi][h][nj * 64 + 32 + l5];
            float16 a0 = __builtin_amdgcn_mfma_f32_32x32x16_bf16(afr, c0.s, z16, 0, 0, 0);
            float16 a1 = __builtin_amdgcn_mfma_f32_32x32x16_bf16(afr, c1.s, z16, 0, 0, 0);
#pragma unroll
            for (int r = 0; r < 16; r++)
                rm[r] = fminf(fminf(a0[r], a1[r]), rm[r]);     // v_min3
            // col-mins over this half's 16 rows; both halves atomicMin-merge
            float cm0 = tree16(a0);
            float cm1 = tree16(a1);
            const int col = c * CHUNKC + j2 * 64 + l5;
            atomicMin(&colpart[col],      __float_as_uint(fmaxf(cm0, 0.0f)));
            atomicMin(&colpart[col + 32], __float_as_uint(fmaxf(cm1, 0.0f)));
            c0 = n0; c1 = n1;
        }
        if (c + 1 < NCHUNKS) convertWrite((c + 1) & 1);      // vmcnt hidden
    }

    // merge block-local col-mins into the 256 KB global plane (16 per thread)
    __syncthreads();
#pragma unroll
    for (int i = 0; i < 16; i++) {
        const int idx = t + i * 256;
        atomicMin(&wsC[(size_t)b * NPTS + idx], colpart[idx]);
    }

    // Row-min: fold the 32 col-slots across lanes (masks 1..16; halves hold
    // disjoint row sets so mask 32 must NOT min-fold).
#pragma unroll
    for (int mask = 1; mask <= 16; mask <<= 1)
#pragma unroll
        for (int r = 0; r < 16; r++)
            rm[r] = fminf(rm[r], __shfl_xor(rm[r], mask, 64));

    float s = 0.0f;
#pragma unroll
    for (int r = 0; r < 16; r++) s += fmaxf(rm[r], 0.0f);
    s += __shfl_xor(s, 32, 64);       // add the other half's 16 rows

    if (lane == 0) wsum[w] = s;
    __syncthreads();
    if (t == 0)
        atomicAdd(out, (wsum[0] + wsum[1] + wsum[2] + wsum[3]) * (1.0f / (float)NPTS));
}

// --------------------------------------------- K2: sum col-mins (256 KB)
__global__ __launch_bounds__(256) void finish_reduce(
    const unsigned* __restrict__ wsC, float* __restrict__ out)
{
    __shared__ float wsum[4];
    const int b = blockIdx.x;
    float v = 0.0f;
#pragma unroll
    for (int i = 0; i < 16; i++)
        v += __uint_as_float(wsC[(size_t)b * NPTS + threadIdx.x + i * 256]);
#pragma unroll
    for (int mask = 1; mask <= 32; mask <<= 1) v += __shfl_xor(v, mask, 64);
    if ((threadIdx.x & 63) == 0) wsum[threadIdx.x >> 6] = v;
    __syncthreads();
    if (threadIdx.x == 0)
        atomicAdd(out, (wsum[0] + wsum[1] + wsum[2] + wsum[3]) * (1.0f / (float)NPTS));
}

// ---------------------------------------------------------------- launch
extern "C" void kernel_launch(void* const* d_in, const int* in_sizes, int n_in,
                              void* d_out, int out_size, void* d_ws, size_t ws_size,
                              hipStream_t stream)
{
    const float* src = (const float*)d_in[0];
    const float* tgt = (const float*)d_in[1];
    float* out = (float*)d_out;
    unsigned* wsC = (unsigned*)d_ws;              // 16 x 4096 x 4B = 256 KB

    hipMemsetAsync(out, 0, sizeof(float), stream);
    hipMemsetAsync(wsC, 0xFF, (size_t)BATCH * NPTS * sizeof(unsigned), stream);
    chamfer_main <<<BATCH * NSTRIPS, 256, 0, stream>>>(src, tgt, wsC, out);
    finish_reduce<<<BATCH, 256, 0, stream>>>(wsC, out);
}

// Round 4
// 78.668 us; speedup vs baseline: 7.3734x; 1.0487x over previous
//
#include <hip/hip_runtime.h>
#include <hip/hip_bf16.h>

// Chamfer distance, B=16, N=M=4096, D=3, fp32 — one-pass MFMA, both mins,
// latency-hiding version.
//
// Round-3 post-mortem: kernel is per-step LATENCY-bound (64 j2-steps/wave,
// MFMA->fold dependency chain, only 2 blocks/CU resident because grid=512).
// Fix: split cols 2-way -> grid 1024 (= exactly 4 blocks/CU), 32 steps/wave,
// LDS trimmed to 40KB exactly (32KB dbuf + 8KB colpart, rowbuf overlaps
// colpart) so 4 blocks/CU fit -> 4 waves/SIMD to hide per-step stalls.
//   row-min -> cham_x : rm[16] accum + cross-lane fold; cross-block (col
//                       half) merge via clamped uint atomicMin -> wsR.
//   col-min -> cham_y : per-step min3 tree -> LDS atomicMin plane; one
//                       global atomicMin per col per block -> wsC.
// finish_reduce sums both 256KB planes. ws total 512KB (rounds 1-2 showed
// multi-MB ws streaming is pathological on this harness).

#define BATCH   16
#define NPTS    4096
#define NSTRIPS 32                 // 128 rows per block
#define NH      2                  // col halves
#define COLS_PB 2048               // cols per block
#define CHUNKC  512
#define NCHUNKS (COLS_PB / CHUNKC) // 4
#define NSTEP   (CHUNKC / 64)      // 8 j2-steps per chunk

typedef __attribute__((ext_vector_type(8)))  short short8;
typedef __attribute__((ext_vector_type(16))) float float16;

union U4S8 { uint4 u; short8 s; };

__device__ inline unsigned int bfb(float v) {
    __hip_bfloat16 h = __float2bfloat16(v);
    unsigned short u; __builtin_memcpy(&u, &h, 2);
    return (unsigned int)u;
}
__device__ inline float bff(float v) { return __bfloat162float(__float2bfloat16(v)); }

#define ONEB 0x3F80u

// A (query) slots: [xh yh zh xh yh zh xl yl | zl fh fl 1 1 0 0 0]
__device__ inline void buildA(float x, float y, float z, uint4& w0, uint4& w1) {
    float xhf = bff(x), yhf = bff(y), zhf = bff(z);
    float f = fmaf(x, x, fmaf(y, y, z * z));
    float fhf = bff(f);
    unsigned xh = bfb(xhf), yh = bfb(yhf), zh = bfb(zhf);
    unsigned xl = bfb(x - xhf), yl = bfb(y - yhf), zl = bfb(z - zhf);
    unsigned fh = bfb(fhf), fl = bfb(f - fhf);
    w0 = make_uint4(xh | (yh << 16), zh | (xh << 16),
                    yh | (zh << 16), xl | (yl << 16));
    w1 = make_uint4(zl | (fh << 16), fl | (ONEB << 16), ONEB, 0u);
}

// B (target) slots: [-2xh -2yh -2zh -2xl -2yl -2zl -2xh -2yh | -2zh 1 1 fh fl 0 0 0]
__device__ inline void buildB(float x, float y, float z, uint4& w0, uint4& w1) {
    float xhf = bff(x), yhf = bff(y), zhf = bff(z);
    float f = fmaf(x, x, fmaf(y, y, z * z));
    float fhf = bff(f);
    unsigned a = bfb(-2.0f * xhf), b = bfb(-2.0f * yhf), c = bfb(-2.0f * zhf);
    unsigned d = bfb(-2.0f * (x - xhf)), e = bfb(-2.0f * (y - yhf)),
             g = bfb(-2.0f * (z - zhf));
    unsigned fh = bfb(fhf), fl = bfb(f - fhf);
    w0 = make_uint4(a | (b << 16), c | (d << 16),
                    e | (g << 16), a | (b << 16));
    w1 = make_uint4(c | (ONEB << 16), ONEB | (fh << 16), fl, 0u);
}

// min over the 16 regs (this half's 16 rows) of one 32x32 MFMA result.
__device__ inline float tree16(const float16& a) {
    float m0 = fminf(fminf(a[0],  a[1]),  a[2]);    // v_min3
    float m1 = fminf(fminf(a[3],  a[4]),  a[5]);
    float m2 = fminf(fminf(a[6],  a[7]),  a[8]);
    float m3 = fminf(fminf(a[9],  a[10]), a[11]);
    float m4 = fminf(fminf(a[12], a[13]), a[14]);
    float p0 = fminf(fminf(m0, m1), a[15]);
    float p1 = fminf(fminf(m2, m3), m4);
    return fminf(p0, p1);
}

__global__ __launch_bounds__(256, 4) void chamfer_main(
    const float* __restrict__ src, const float* __restrict__ tgt,
    unsigned* __restrict__ wsC, unsigned* __restrict__ wsR)
{
    __shared__ uint4 sbuf[2][2][CHUNKC];     // [buf][half][pt] = 32 KB
    __shared__ unsigned colpart[COLS_PB];    // 8 KB (rowbuf reuses [0:128))

    int blk = blockIdx.x;
    const int strip = blk & (NSTRIPS - 1); blk >>= 5;
    const int b     = blk & 15;            blk >>= 4;
    const int q     = blk;                 // col half 0/1
    const int qoff  = q * COLS_PB;

    const int t    = threadIdx.x;
    const int lane = t & 63;
    const int w    = t >> 6;
    const int h    = lane >> 5;
    const int l5   = lane & 31;

    const float* Araw = src + (size_t)b * NPTS * 3;   // rows (queries)
    const float* Braw = tgt + (size_t)b * NPTS * 3;   // cols (targets)

    // A fragment: one 32-row group per wave (128 rows per block)
    short8 afr;
    {
        int row = strip * 128 + w * 32 + l5;
        uint4 w0, w1;
        buildA(Araw[3 * row], Araw[3 * row + 1], Araw[3 * row + 2], w0, w1);
        U4S8 tt; tt.u = h ? w1 : w0;
        afr = tt.s;
    }

    // init block-local col-min plane (8 entries per thread)
#pragma unroll
    for (int i = 0; i < COLS_PB / 256; i++) colpart[t + i * 256] = 0xFFFFFFFFu;

    // Pipelined B staging: raw loads (regs) early, convert + ds_write late.
    float nx[2][3];
    auto loadRaw = [&](int c) {
#pragma unroll
        for (int k = 0; k < 2; k++) {
            int p = qoff + c * CHUNKC + t + k * 256;
            nx[k][0] = Braw[3 * p + 0];
            nx[k][1] = Braw[3 * p + 1];
            nx[k][2] = Braw[3 * p + 2];
        }
    };
    auto convertWrite = [&](int bi) {
#pragma unroll
        for (int k = 0; k < 2; k++) {
            int lp = t + k * 256;
            uint4 w0, w1;
            buildB(nx[k][0], nx[k][1], nx[k][2], w0, w1);
            sbuf[bi][0][lp] = w0;
            sbuf[bi][1][lp] = w1;
        }
    };

    const float16 z16 = {0.f,0.f,0.f,0.f,0.f,0.f,0.f,0.f,
                         0.f,0.f,0.f,0.f,0.f,0.f,0.f,0.f};
    float rm[16];
#pragma unroll
    for (int r = 0; r < 16; r++) rm[r] = 1e30f;

    loadRaw(0);
    convertWrite(0);
    for (int c = 0; c < NCHUNKS; c++) {
        __syncthreads();              // buf[c&1] written; prior-iter reads done
        if (c + 1 < NCHUNKS) loadRaw(c + 1);   // issue, don't wait
        const int bi = c & 1;

        U4S8 c0, c1, n0, n1;
        c0.u = sbuf[bi][h][l5];
        c1.u = sbuf[bi][h][32 + l5];
#pragma unroll 4
        for (int j2 = 0; j2 < NSTEP; j2++) {
            int nj = (j2 + 1) & (NSTEP - 1);          // wrap re-read: harmless
            n0.u = sbuf[bi][h][nj * 64 + l5];
            n1.u = sbuf[bi][h][nj * 64 + 32 + l5];
            float16 a0 = __builtin_amdgcn_mfma_f32_32x32x16_bf16(afr, c0.s, z16, 0, 0, 0);
            float16 a1 = __builtin_amdgcn_mfma_f32_32x32x16_bf16(afr, c1.s, z16, 0, 0, 0);
#pragma unroll
            for (int r = 0; r < 16; r++)
                rm[r] = fminf(fminf(a0[r], a1[r]), rm[r]);     // v_min3
            // col-mins over this half's 16 rows; both halves atomicMin-merge
            float cm0 = tree16(a0);
            float cm1 = tree16(a1);
            const int col = c * CHUNKC + j2 * 64 + l5;         // block-local
            atomicMin(&colpart[col],      __float_as_uint(fmaxf(cm0, 0.0f)));
            atomicMin(&colpart[col + 32], __float_as_uint(fmaxf(cm1, 0.0f)));
            c0 = n0; c1 = n1;
        }
        if (c + 1 < NCHUNKS) convertWrite((c + 1) & 1);      // vmcnt hidden
    }

    // merge block-local col-mins into the global plane (8 per thread)
    __syncthreads();
#pragma unroll
    for (int i = 0; i < COLS_PB / 256; i++) {
        const int idx = t + i * 256;
        atomicMin(&wsC[(size_t)b * NPTS + qoff + idx], colpart[idx]);
    }

    // Row-min partial (over this block's 2048 cols): fold the 32 col-slots
    // across lanes (masks 1..16; halves hold disjoint row sets).
#pragma unroll
    for (int mask = 1; mask <= 16; mask <<= 1)
#pragma unroll
        for (int r = 0; r < 16; r++)
            rm[r] = fminf(rm[r], __shfl_xor(rm[r], mask, 64));

    // transpose via LDS (reuse colpart[0:128)), then coalesced atomicMin.
    __syncthreads();                 // colpart merge reads done
    if (l5 == 0) {
#pragma unroll
        for (int r = 0; r < 16; r++) {
            const int row = w * 32 + (r & 3) + 8 * (r >> 2) + 4 * h;
            colpart[row] = __float_as_uint(fmaxf(rm[r], 0.0f));
        }
    }
    __syncthreads();
    if (t < 128)
        atomicMin(&wsR[(size_t)b * NPTS + strip * 128 + t], colpart[t]);
}

// ---------------------- K2: sum col-min + row-min planes (2 x 256 KB)
__global__ __launch_bounds__(256) void finish_reduce(
    const unsigned* __restrict__ wsC, const unsigned* __restrict__ wsR,
    float* __restrict__ out)
{
    __shared__ float wsum[4];
    const int b = blockIdx.x;
    float v = 0.0f;
#pragma unroll
    for (int i = 0; i < 16; i++)
        v += __uint_as_float(wsC[(size_t)b * NPTS + threadIdx.x + i * 256]);
#pragma unroll
    for (int i = 0; i < 16; i++)
        v += __uint_as_float(wsR[(size_t)b * NPTS + threadIdx.x + i * 256]);
#pragma unroll
    for (int mask = 1; mask <= 32; mask <<= 1) v += __shfl_xor(v, mask, 64);
    if ((threadIdx.x & 63) == 0) wsum[threadIdx.x >> 6] = v;
    __syncthreads();
    if (threadIdx.x == 0)
        atomicAdd(out, (wsum[0] + wsum[1] + wsum[2] + wsum[3]) * (1.0f / (float)NPTS));
}

// ---------------------------------------------------------------- launch
extern "C" void kernel_launch(void* const* d_in, const int* in_sizes, int n_in,
                              void* d_out, int out_size, void* d_ws, size_t ws_size,
                              hipStream_t stream)
{
    const float* src = (const float*)d_in[0];
    const float* tgt = (const float*)d_in[1];
    float* out = (float*)d_out;
    unsigned* wsC = (unsigned*)d_ws;                      // 256 KB
    unsigned* wsR = wsC + (size_t)BATCH * NPTS;           // 256 KB

    hipMemsetAsync(out, 0, sizeof(float), stream);
    hipMemsetAsync(d_ws, 0xFF, (size_t)2 * BATCH * NPTS * sizeof(unsigned), stream);
    chamfer_main <<<NH * BATCH * NSTRIPS, 256, 0, stream>>>(src, tgt, wsC, wsR);
    finish_reduce<<<BATCH, 256, 0, stream>>>(wsC, wsR, out);
}